// Round 14
// baseline (266.079 us; speedup 1.0000x reference)
//
#include <hip/hip_runtime.h>
#include <math.h>

#define NB 8
#define NP 2048
#define GRID 256        // 8 batches * 32 src-chunks of 64; 1 block/CU
#define THREADS 512     // 8 waves/CU -> 2 waves/SIMD
#define TOLF 1e-4f
#define EPSF 1e-12f

#define AL(p)   __hip_atomic_load((p), __ATOMIC_RELAXED, __HIP_MEMORY_SCOPE_AGENT)
#define AS(p,v) __hip_atomic_store((p), (v), __ATOMIC_RELAXED, __HIP_MEMORY_SCOPE_AGENT)

// identical fmaf structure everywhere => bit-identical transformed points
__device__ inline float3 xform_pt(const float* __restrict__ T,
                                  float x, float y, float z) {
    float3 r;
    r.x = fmaf(T[0], x, fmaf(T[1], y, fmaf(T[2], z, T[9])));
    r.y = fmaf(T[3], x, fmaf(T[4], y, fmaf(T[5], z, T[10])));
    r.z = fmaf(T[6], x, fmaf(T[7], y, fmaf(T[8], z, T[11])));
    return r;
}

// ---- 3x3 Kabsch: fp64 sums/H/det/compose, fp32 Jacobi SVD ----
__device__ void kabsch3x3(const double Spq[9], const double Sp[3], const double Sq[3],
                          double R[9], double t[3]) {
    const double invN = 1.0 / (double)NP;
    double cs[3], ct[3];
#pragma unroll
    for (int i = 0; i < 3; ++i) { cs[i] = Sp[i] * invN; ct[i] = Sq[i] * invN; }
    double Hd[9];
#pragma unroll
    for (int i = 0; i < 3; ++i)
#pragma unroll
        for (int j = 0; j < 3; ++j)
            Hd[i * 3 + j] = Spq[i * 3 + j] - (double)NP * cs[i] * ct[j];

    float Bc[3][3], V[3][3];
#pragma unroll
    for (int j = 0; j < 3; ++j)
#pragma unroll
        for (int i = 0; i < 3; ++i) {
            Bc[j][i] = (float)Hd[i * 3 + j];
            V[j][i]  = (i == j) ? 1.0f : 0.0f;
        }
    for (int sweep = 0; sweep < 12; ++sweep) {
        bool rotated = false;
        for (int p = 0; p < 2; ++p)
            for (int q = p + 1; q < 3; ++q) {
                float app = 0.f, aqq = 0.f, apq = 0.f;
#pragma unroll
                for (int i = 0; i < 3; ++i) {
                    app = fmaf(Bc[p][i], Bc[p][i], app);
                    aqq = fmaf(Bc[q][i], Bc[q][i], aqq);
                    apq = fmaf(Bc[p][i], Bc[q][i], apq);
                }
                if (apq * apq > 1e-24f + 1e-12f * app * aqq) {
                    rotated = true;
                    float tau = (aqq - app) / (2.0f * apq);
                    float tt  = (tau >= 0.f ? 1.0f : -1.0f) /
                                (fabsf(tau) + sqrtf(fmaf(tau, tau, 1.0f)));
                    float c   = 1.0f / sqrtf(fmaf(tt, tt, 1.0f));
                    float sn  = c * tt;
#pragma unroll
                    for (int i = 0; i < 3; ++i) {
                        float bp = Bc[p][i], bq = Bc[q][i];
                        Bc[p][i] = c * bp - sn * bq;
                        Bc[q][i] = sn * bp + c * bq;
                        float vp = V[p][i], vq = V[q][i];
                        V[p][i] = c * vp - sn * vq;
                        V[q][i] = sn * vp + c * vq;
                    }
                }
            }
        if (!rotated) break;
    }
    float sv[3], U[3][3];
#pragma unroll
    for (int j = 0; j < 3; ++j) {
        sv[j] = sqrtf(Bc[j][0] * Bc[j][0] + Bc[j][1] * Bc[j][1] + Bc[j][2] * Bc[j][2]);
        float inv = sv[j] > 0.f ? 1.0f / sv[j] : 0.f;
#pragma unroll
        for (int i = 0; i < 3; ++i) U[j][i] = Bc[j][i] * inv;
    }
    double detH = Hd[0] * (Hd[4] * Hd[8] - Hd[5] * Hd[7])
                - Hd[1] * (Hd[3] * Hd[8] - Hd[5] * Hd[6])
                + Hd[2] * (Hd[3] * Hd[7] - Hd[4] * Hd[6]);
    float d = (detH >= 0.0) ? 1.0f : -1.0f;
    int o[3] = {0, 1, 2};
    if (sv[o[0]] < sv[o[1]]) { int tmp = o[0]; o[0] = o[1]; o[1] = tmp; }
    if (sv[o[0]] < sv[o[2]]) { int tmp = o[0]; o[0] = o[2]; o[2] = tmp; }
    if (sv[o[1]] < sv[o[2]]) { int tmp = o[1]; o[1] = o[2]; o[2] = tmp; }
    float sg[3] = {1.0f, 1.0f, d};
#pragma unroll
    for (int i = 0; i < 3; ++i)
#pragma unroll
        for (int j = 0; j < 3; ++j) {
            float acc = 0.0f;
#pragma unroll
            for (int k = 0; k < 3; ++k) acc += sg[k] * V[o[k]][i] * U[o[k]][j];
            R[i * 3 + j] = (double)acc;
        }
#pragma unroll
    for (int i = 0; i < 3; ++i)
        t[i] = ct[i] - (R[i * 3 + 0] * cs[0] + R[i * 3 + 1] * cs[1] + R[i * 3 + 2] * cs[2]);
}

// ---------------- init: reset barrier flags ----------------
__global__ __launch_bounds__(256) void icp_init(unsigned* __restrict__ flags) {
    flags[threadIdx.x] = 0u;
}

// ---------------- main (MEASUREMENT BUILD: compute phases doubled) ----------
// Identical result to r13 (idempotent re-execution of NN scan, slice merge,
// and partial reduce). dur_us now = 2*compute + 1*(sync+serial).
__global__ __launch_bounds__(THREADS, 1) void icp_main(
        const float* __restrict__ psrc, const float* __restrict__ ptgt,
        double* __restrict__ partial,    // [2][256][16] parity double-buffered
        unsigned* __restrict__ flags,    // [256] per-block arrival (monotone it)
        double* __restrict__ Tcs,        // [8][11][12] trajectories (t=0..10)
        unsigned* __restrict__ cbits) {  // [8][16] convergence bit per iter
    __shared__ float4 tg[2112];          // targets, padded: idx = j + (j>>5)
    __shared__ float4 ps[64];            // transformed src pts (x,y,z,|P|^2)
    __shared__ float2 comb[64][66];      // [slice][src] winners
    __shared__ float  TcL[12];
    __shared__ double TcA[12];

    const int tid   = threadIdx.x;
    const int blk   = blockIdx.x;
    const int b     = blk >> 5;          // batch
    const int sc    = blk & 31;          // src chunk
    const int slice = tid & 63;          // target slice (32 targets)
    const int g     = tid >> 6;          // src group (8 pts)

    float errL = 0.0f;

    const float* tb = ptgt + b * NP * 3;
    for (int j = tid; j < NP; j += THREADS) {
        float tx = tb[3 * j + 0], ty = tb[3 * j + 1], tz = tb[3 * j + 2];
        tg[j + (j >> 5)] = make_float4(tx, ty, tz,
                                       0.5f * (tx * tx + ty * ty + tz * tz));
    }
    if (tid < 12) {
        float idv = (tid == 0 || tid == 4 || tid == 8) ? 1.0f : 0.0f;
        TcL[tid] = idv;
        TcA[tid] = (double)idv;
        if (sc == 0) AS(&Tcs[(b * 11 + 0) * 12 + tid], (double)idv);
    }
    __syncthreads();

    for (int it = 1; it <= 10; ++it) {
        if (tid < 64) {
            const float* pp = psrc + (b * NP + sc * 64 + tid) * 3;
            float3 P = xform_pt(TcL, pp[0], pp[1], pp[2]);
            ps[tid] = make_float4(P.x, P.y, P.z,
                                  P.x * P.x + P.y * P.y + P.z * P.z);
        }
        __syncthreads();

        float sx[8], sy[8], sz[8], sm[8];
        int jm[8];
#pragma unroll
        for (int k = 0; k < 8; ++k) {
            float4 P = ps[g * 8 + k];
            sx[k] = P.x; sy[k] = P.y; sz[k] = P.z;
            sm[k] = INFINITY; jm[k] = 0;
        }
        const int base = slice * 33, jbase = slice * 32;
        // ======== NN scan — pass 1 ========
#pragma unroll 4
        for (int i = 0; i < 32; ++i) {
            float4 t = tg[base + i];
            int j = jbase + i;
#pragma unroll
            for (int k = 0; k < 8; ++k) {
                float s = fmaf(-sx[k], t.x, fmaf(-sy[k], t.y, fmaf(-sz[k], t.z, t.w)));
                if (s < sm[k]) { sm[k] = s; jm[k] = j; }
            }
        }
        asm volatile("" ::: "memory");   // block CSE with pass 2
        // ======== NN scan — pass 2 (idempotent duplicate: MEASUREMENT) ========
#pragma unroll 4
        for (int i = 0; i < 32; ++i) {
            float4 t = tg[base + i];
            int j = jbase + i;
#pragma unroll
            for (int k = 0; k < 8; ++k) {
                float s = fmaf(-sx[k], t.x, fmaf(-sy[k], t.y, fmaf(-sz[k], t.z, t.w)));
                if (s < sm[k]) { sm[k] = s; jm[k] = j; }   // strict < : no change
            }
        }
#pragma unroll
        for (int k = 0; k < 8; ++k)
            comb[slice][g * 8 + k] = make_float2(sm[k], __int_as_float(jm[k]));
        __syncthreads();

        double* pbase = partial + (size_t)(it & 1) * GRID * 16;

        if (tid < 64) {
            // ======== slice merge — pass 1 ========
            float fb = INFINITY; int fj = 0;
#pragma unroll 8
            for (int q = 0; q < 64; ++q) {
                float2 e = comb[q][tid];
                if (e.x < fb) { fb = e.x; fj = __float_as_int(e.y); }
            }
            asm volatile("" ::: "memory");
            // ======== slice merge — pass 2 (idempotent: MEASUREMENT) ========
#pragma unroll 8
            for (int q = 0; q < 64; ++q) {
                float2 e = comb[q][tid];
                if (e.x < fb) { fb = e.x; fj = __float_as_int(e.y); }
            }
            float4 P = ps[tid];
            float d2 = fmaf(2.0f, fb, P.w);
            float dist = sqrtf(fmaxf(d2, EPSF));
            float4 Q = tg[fj + (fj >> 5)];

            double v[16];
            v[0] = dist;
            v[1] = P.x; v[2] = P.y; v[3] = P.z;
            v[4] = Q.x; v[5] = Q.y; v[6] = Q.z;
            v[7]  = (double)P.x * Q.x; v[8]  = (double)P.x * Q.y; v[9]  = (double)P.x * Q.z;
            v[10] = (double)P.y * Q.x; v[11] = (double)P.y * Q.y; v[12] = (double)P.y * Q.z;
            v[13] = (double)P.z * Q.x; v[14] = (double)P.z * Q.y; v[15] = (double)P.z * Q.z;
#pragma unroll
            for (int k = 0; k < 16; ++k) {
                double x = v[k];
#pragma unroll
                for (int off = 32; off > 0; off >>= 1) x += __shfl_down(x, off);
                v[k] = x;
            }
            if (tid == 0) {
                double* dst = pbase + blk * 16;
#pragma unroll
                for (int k = 0; k < 16; ++k) AS(dst + k, v[k]);
                asm volatile("s_waitcnt vmcnt(0)" ::: "memory");
                AS(&flags[blk], (unsigned)it);
            }
        } else if (tid < 128) {
            int l = tid - 64;
            bool ok;
            do {
                ok = (l < 32) ? (AL(&flags[b * 32 + l]) >= (unsigned)it) : true;
                if (!__all(ok)) __builtin_amdgcn_s_sleep(1); else break;
            } while (true);
        }
        __syncthreads();

        if (tid < 32) {
            double acc[16];
            // ======== partial read+reduce — pass 1 + pass 2 (MEASUREMENT) ====
            for (int rep = 0; rep < 2; ++rep) {
                const double* pp2 = pbase + (b * 32 + tid) * 16;
#pragma unroll
                for (int k = 0; k < 16; ++k) acc[k] = AL(pp2 + k);
#pragma unroll
                for (int k = 0; k < 16; ++k) {
                    double x = acc[k];
                    x += __shfl_down(x, 16);
                    x += __shfl_down(x, 8);
                    x += __shfl_down(x, 4);
                    x += __shfl_down(x, 2);
                    x += __shfl_down(x, 1);
                    acc[k] = x;
                }
                asm volatile("" ::: "memory");
            }
            if (tid == 0) {
                float errnew = (float)(acc[0] * (1.0 / (double)NP));
                unsigned cb = (fabsf(errnew - errL) < TOLF) ? 1u : 0u;
                errL = errnew;
                double R[9], t[3];
                kabsch3x3(&acc[7], &acc[1], &acc[4], R, t);
                double To[12];
#pragma unroll
                for (int k = 0; k < 12; ++k) To[k] = TcA[k];
#pragma unroll
                for (int i = 0; i < 3; ++i) {
#pragma unroll
                    for (int j = 0; j < 3; ++j)
                        TcA[i * 3 + j] = R[i * 3 + 0] * To[0 + j]
                                       + R[i * 3 + 1] * To[3 + j]
                                       + R[i * 3 + 2] * To[6 + j];
                    TcA[9 + i] = R[i * 3 + 0] * To[9] + R[i * 3 + 1] * To[10]
                               + R[i * 3 + 2] * To[11] + t[i];
                }
                if (sc == 0) {
#pragma unroll
                    for (int k = 0; k < 12; ++k)
                        AS(&Tcs[(b * 11 + it) * 12 + k], TcA[k]);
                    AS(&cbits[b * 16 + it], cb);
                }
            }
        }
        __syncthreads();
        if (tid < 12) TcL[tid] = (float)TcA[tid];
        __syncthreads();
    }
}

// ---------------- resolver: find freeze step k*, emit Tc(k*-1) ----------------
__global__ __launch_bounds__(64) void icp_resolve(const double* __restrict__ Tcs,
                                                  const unsigned* __restrict__ cbits,
                                                  float* __restrict__ out) {
    __shared__ int ksel;
    int tid = threadIdx.x;
    if (tid == 0) {
        int sel = 10;
        for (int t = 1; t <= 10; ++t) {
            bool all = true;
            for (int b2 = 0; b2 < NB; ++b2) all = all && (cbits[b2 * 16 + t] != 0u);
            if (all) { sel = t - 1; break; }
        }
        ksel = sel;
    }
    __syncthreads();
    if (tid < NB) {
        const double* T = Tcs + ((size_t)tid * 11 + ksel) * 12;
        float* o = out + tid * 12;
#pragma unroll
        for (int i = 0; i < 3; ++i) {
#pragma unroll
            for (int j = 0; j < 3; ++j) o[i * 4 + j] = (float)T[i * 3 + j];
            o[i * 4 + 3] = (float)T[9 + i];
        }
    }
}

extern "C" void kernel_launch(void* const* d_in, const int* in_sizes, int n_in,
                              void* d_out, int out_size, void* d_ws, size_t ws_size,
                              hipStream_t stream) {
    const float* psrc = (const float*)d_in[0];
    const float* ptgt = (const float*)d_in[1];
    float* out = (float*)d_out;

    char* ws = (char*)d_ws;
    size_t off = 0;
    double* partial = (double*)(ws + off); off += 2ull * GRID * 16 * sizeof(double);
    unsigned* flags = (unsigned*)(ws + off); off += GRID * sizeof(unsigned);
    double* Tcs   = (double*)(ws + off);   off += (size_t)NB * 11 * 12 * sizeof(double);
    unsigned* cbits = (unsigned*)(ws + off); off += NB * 16 * sizeof(unsigned);

    icp_init<<<1, 256, 0, stream>>>(flags);
    icp_main<<<GRID, THREADS, 0, stream>>>(psrc, ptgt, partial, flags, Tcs, cbits);
    icp_resolve<<<1, 64, 0, stream>>>(Tcs, cbits, out);
}

// Round 15
// 180.314 us; speedup vs baseline: 1.4756x; 1.4756x over previous
//
#include <hip/hip_runtime.h>
#include <math.h>

#define NB 8
#define NP 2048
#define GRID 256        // 8 batches * 32 src-chunks of 64; 1 block/CU
#define THREADS 512     // 8 waves/CU
#define TOLF 1e-4f
#define EPSF 1e-12f

#define AL(p)   __hip_atomic_load((p), __ATOMIC_RELAXED, __HIP_MEMORY_SCOPE_AGENT)
#define AS(p,v) __hip_atomic_store((p), (v), __ATOMIC_RELAXED, __HIP_MEMORY_SCOPE_AGENT)

typedef __attribute__((ext_vector_type(2))) float f32x2;

// identical fmaf structure everywhere => bit-identical transformed points
__device__ inline float3 xform_pt(const float* __restrict__ T,
                                  float x, float y, float z) {
    float3 r;
    r.x = fmaf(T[0], x, fmaf(T[1], y, fmaf(T[2], z, T[9])));
    r.y = fmaf(T[3], x, fmaf(T[4], y, fmaf(T[5], z, T[10])));
    r.z = fmaf(T[6], x, fmaf(T[7], y, fmaf(T[8], z, T[11])));
    return r;
}

// ---- 3x3 Kabsch: fp64 sums/H/det/compose, fp32 Jacobi SVD ----
__device__ void kabsch3x3(const double Spq[9], const double Sp[3], const double Sq[3],
                          double R[9], double t[3]) {
    const double invN = 1.0 / (double)NP;
    double cs[3], ct[3];
#pragma unroll
    for (int i = 0; i < 3; ++i) { cs[i] = Sp[i] * invN; ct[i] = Sq[i] * invN; }
    double Hd[9];
#pragma unroll
    for (int i = 0; i < 3; ++i)
#pragma unroll
        for (int j = 0; j < 3; ++j)
            Hd[i * 3 + j] = Spq[i * 3 + j] - (double)NP * cs[i] * ct[j];

    float Bc[3][3], V[3][3];
#pragma unroll
    for (int j = 0; j < 3; ++j)
#pragma unroll
        for (int i = 0; i < 3; ++i) {
            Bc[j][i] = (float)Hd[i * 3 + j];
            V[j][i]  = (i == j) ? 1.0f : 0.0f;
        }
    for (int sweep = 0; sweep < 12; ++sweep) {
        bool rotated = false;
        for (int p = 0; p < 2; ++p)
            for (int q = p + 1; q < 3; ++q) {
                float app = 0.f, aqq = 0.f, apq = 0.f;
#pragma unroll
                for (int i = 0; i < 3; ++i) {
                    app = fmaf(Bc[p][i], Bc[p][i], app);
                    aqq = fmaf(Bc[q][i], Bc[q][i], aqq);
                    apq = fmaf(Bc[p][i], Bc[q][i], apq);
                }
                if (apq * apq > 1e-24f + 1e-12f * app * aqq) {
                    rotated = true;
                    float tau = (aqq - app) / (2.0f * apq);
                    float tt  = (tau >= 0.f ? 1.0f : -1.0f) /
                                (fabsf(tau) + sqrtf(fmaf(tau, tau, 1.0f)));
                    float c   = 1.0f / sqrtf(fmaf(tt, tt, 1.0f));
                    float sn  = c * tt;
#pragma unroll
                    for (int i = 0; i < 3; ++i) {
                        float bp = Bc[p][i], bq = Bc[q][i];
                        Bc[p][i] = c * bp - sn * bq;
                        Bc[q][i] = sn * bp + c * bq;
                        float vp = V[p][i], vq = V[q][i];
                        V[p][i] = c * vp - sn * vq;
                        V[q][i] = sn * vp + c * vq;
                    }
                }
            }
        if (!rotated) break;
    }
    float sv[3], U[3][3];
#pragma unroll
    for (int j = 0; j < 3; ++j) {
        sv[j] = sqrtf(Bc[j][0] * Bc[j][0] + Bc[j][1] * Bc[j][1] + Bc[j][2] * Bc[j][2]);
        float inv = sv[j] > 0.f ? 1.0f / sv[j] : 0.f;
#pragma unroll
        for (int i = 0; i < 3; ++i) U[j][i] = Bc[j][i] * inv;
    }
    double detH = Hd[0] * (Hd[4] * Hd[8] - Hd[5] * Hd[7])
                - Hd[1] * (Hd[3] * Hd[8] - Hd[5] * Hd[6])
                + Hd[2] * (Hd[3] * Hd[7] - Hd[4] * Hd[6]);
    float d = (detH >= 0.0) ? 1.0f : -1.0f;
    int o[3] = {0, 1, 2};
    if (sv[o[0]] < sv[o[1]]) { int tmp = o[0]; o[0] = o[1]; o[1] = tmp; }
    if (sv[o[0]] < sv[o[2]]) { int tmp = o[0]; o[0] = o[2]; o[2] = tmp; }
    if (sv[o[1]] < sv[o[2]]) { int tmp = o[1]; o[1] = o[2]; o[2] = tmp; }
    float sg[3] = {1.0f, 1.0f, d};
#pragma unroll
    for (int i = 0; i < 3; ++i)
#pragma unroll
        for (int j = 0; j < 3; ++j) {
            float acc = 0.0f;
#pragma unroll
            for (int k = 0; k < 3; ++k) acc += sg[k] * V[o[k]][i] * U[o[k]][j];
            R[i * 3 + j] = (double)acc;
        }
#pragma unroll
    for (int i = 0; i < 3; ++i)
        t[i] = ct[i] - (R[i * 3 + 0] * cs[0] + R[i * 3 + 1] * cs[1] + R[i * 3 + 2] * cs[2]);
}

// ---------------- init: reset barrier flags ----------------
__global__ __launch_bounds__(256) void icp_init(unsigned* __restrict__ flags) {
    flags[threadIdx.x] = 0u;
}

// ---------------- main: 8 independent batches, per-batch 32-block barrier ----
// Targets in LDS as padded component PLANES (float2, stride 17/slice) so the
// NN inner loop evaluates 2 targets per step via v_pk_fma_f32.
__global__ __launch_bounds__(THREADS, 1) void icp_main(
        const float* __restrict__ psrc, const float* __restrict__ ptgt,
        double* __restrict__ partial,    // [2][256][16] parity double-buffered
        unsigned* __restrict__ flags,    // [256] per-block arrival (monotone it)
        double* __restrict__ Tcs,        // [8][11][12] trajectories (t=0..10)
        unsigned* __restrict__ cbits) {  // [8][16] convergence bit per iter
    __shared__ f32x2 tgx[1088], tgy[1088], tgz[1088], tgw[1088]; // 64 slices x 17
    __shared__ float4 ps[64];            // transformed src pts (x,y,z,|P|^2)
    __shared__ float2 comb[64][66];      // [slice][src] winners
    __shared__ float2 comb2[8][66];      // stage-A merged winners
    __shared__ float  TcL[12];
    __shared__ double TcA[12];

    const int tid   = threadIdx.x;
    const int blk   = blockIdx.x;
    const int b     = blk >> 5;          // batch
    const int sc    = blk & 31;          // src chunk
    const int slice = tid & 63;          // target slice (32 targets)
    const int g     = tid >> 6;          // src group (8 pts) == wave id

    float errL = 0.0f;

    // stage all 2048 targets as planes: float index = (j>>5)*34 + (j&31)
    const float* tb = ptgt + b * NP * 3;
    for (int j = tid; j < NP; j += THREADS) {
        float tx = tb[3 * j + 0], ty = tb[3 * j + 1], tz = tb[3 * j + 2];
        int fi = (j >> 5) * 34 + (j & 31);
        ((float*)tgx)[fi] = tx;
        ((float*)tgy)[fi] = ty;
        ((float*)tgz)[fi] = tz;
        ((float*)tgw)[fi] = 0.5f * (tx * tx + ty * ty + tz * tz);
    }
    if (tid < 12) {
        float idv = (tid == 0 || tid == 4 || tid == 8) ? 1.0f : 0.0f;
        TcL[tid] = idv;
        TcA[tid] = (double)idv;
        if (sc == 0) AS(&Tcs[(b * 11 + 0) * 12 + tid], (double)idv);
    }
    __syncthreads();

    for (int it = 1; it <= 10; ++it) {
        // ---- transform this chunk's 64 src points with current TcL ----
        if (tid < 64) {
            const float* pp = psrc + (b * NP + sc * 64 + tid) * 3;
            float3 P = xform_pt(TcL, pp[0], pp[1], pp[2]);
            ps[tid] = make_float4(P.x, P.y, P.z,
                                  P.x * P.x + P.y * P.y + P.z * P.z);
        }
        __syncthreads();

        // ---- NN: 8 src pts/thread x 32 targets (16 pairs) of this slice ----
        f32x2 nx[8], ny[8], nz[8];       // negated broadcast pairs
        float sm[8];
        int jm[8];
#pragma unroll
        for (int k = 0; k < 8; ++k) {
            float4 P = ps[g * 8 + k];
            nx[k] = (f32x2){-P.x, -P.x};
            ny[k] = (f32x2){-P.y, -P.y};
            nz[k] = (f32x2){-P.z, -P.z};
            sm[k] = INFINITY; jm[k] = 0;
        }
        const int pb = slice * 17, jbase = slice * 32;
#pragma unroll 4
        for (int p = 0; p < 16; ++p) {
            f32x2 tx2 = tgx[pb + p];
            f32x2 ty2 = tgy[pb + p];
            f32x2 tz2 = tgz[pb + p];
            f32x2 tw2 = tgw[pb + p];
            int jj = jbase + 2 * p;
#pragma unroll
            for (int k = 0; k < 8; ++k) {
                f32x2 a;
                // a = (-sz)*tz + tw ; a += (-sy)*ty ; a += (-sx)*tx (same
                // nesting as scalar fmaf chain => bit-identical scores)
                asm("v_pk_fma_f32 %0, %1, %2, %3"
                    : "=v"(a) : "v"(nz[k]), "v"(tz2), "v"(tw2));
                asm("v_pk_fma_f32 %0, %1, %2, %0"
                    : "+v"(a) : "v"(ny[k]), "v"(ty2));
                asm("v_pk_fma_f32 %0, %1, %2, %0"
                    : "+v"(a) : "v"(nx[k]), "v"(tx2));
                float m2 = fminf(a.x, a.y);
                int js = (a.x <= a.y) ? jj : jj + 1;   // tie -> lower j
                if (m2 < sm[k]) jm[k] = js;            // strict < : first-min
                sm[k] = fminf(sm[k], m2);
            }
        }
#pragma unroll
        for (int k = 0; k < 8; ++k)
            comb[slice][g * 8 + k] = make_float2(sm[k], __int_as_float(jm[k]));
        __syncthreads();

        // ---- stage A: each wave merges its 8 slices (ascending order) ----
        {
            int l = tid & 63;
            float fb = INFINITY; int fj = 0;
#pragma unroll
            for (int q = 0; q < 8; ++q) {
                float2 e = comb[g * 8 + q][l];
                if (e.x < fb) { fb = e.x; fj = __float_as_int(e.y); }
            }
            comb2[g][l] = make_float2(fb, __int_as_float(fj));
        }
        __syncthreads();

        double* pbase = partial + (size_t)(it & 1) * GRID * 16;

        // ---- wave 0: final merge + fp64 sums + publish; wave 1: poll ----
        if (tid < 64) {
            float fb = INFINITY; int fj = 0;
#pragma unroll
            for (int q = 0; q < 8; ++q) {            // ascending: first-min
                float2 e = comb2[q][tid];
                if (e.x < fb) { fb = e.x; fj = __float_as_int(e.y); }
            }
            float4 P = ps[tid];
            float d2 = fmaf(2.0f, fb, P.w);
            float dist = sqrtf(fmaxf(d2, EPSF));
            int qp = (fj >> 5) * 17 + ((fj & 31) >> 1);
            f32x2 qx2 = tgx[qp], qy2 = tgy[qp], qz2 = tgz[qp];
            float Qx = (fj & 1) ? qx2.y : qx2.x;
            float Qy = (fj & 1) ? qy2.y : qy2.x;
            float Qz = (fj & 1) ? qz2.y : qz2.x;

            double v[16];
            v[0] = dist;
            v[1] = P.x; v[2] = P.y; v[3] = P.z;
            v[4] = Qx;  v[5] = Qy;  v[6] = Qz;
            v[7]  = (double)P.x * Qx; v[8]  = (double)P.x * Qy; v[9]  = (double)P.x * Qz;
            v[10] = (double)P.y * Qx; v[11] = (double)P.y * Qy; v[12] = (double)P.y * Qz;
            v[13] = (double)P.z * Qx; v[14] = (double)P.z * Qy; v[15] = (double)P.z * Qz;
#pragma unroll
            for (int k = 0; k < 16; ++k) {
                double x = v[k];
#pragma unroll
                for (int off = 32; off > 0; off >>= 1) x += __shfl_down(x, off);
                v[k] = x;
            }
            if (tid == 0) {
                double* dst = pbase + blk * 16;
#pragma unroll
                for (int k = 0; k < 16; ++k) AS(dst + k, v[k]);
                asm volatile("s_waitcnt vmcnt(0)" ::: "memory");
                AS(&flags[blk], (unsigned)it);
            }
        } else if (tid < 128) {
            int l = tid - 64;
            bool ok;
            do {
                ok = (l < 32) ? (AL(&flags[b * 32 + l]) >= (unsigned)it) : true;
                if (!__all(ok)) __builtin_amdgcn_s_sleep(1); else break;
            } while (true);
        }
        __syncthreads();

        // ---- lanes 0-31: read batch partials + fixed-order reduce + Kabsch ----
        if (tid < 32) {
            double acc[16];
            const double* pp2 = pbase + (b * 32 + tid) * 16;
#pragma unroll
            for (int k = 0; k < 16; ++k) acc[k] = AL(pp2 + k);
#pragma unroll
            for (int k = 0; k < 16; ++k) {
                double x = acc[k];
                x += __shfl_down(x, 16);
                x += __shfl_down(x, 8);
                x += __shfl_down(x, 4);
                x += __shfl_down(x, 2);
                x += __shfl_down(x, 1);
                acc[k] = x;
            }
            if (tid == 0) {
                float errnew = (float)(acc[0] * (1.0 / (double)NP));
                unsigned cb = (fabsf(errnew - errL) < TOLF) ? 1u : 0u;
                errL = errnew;
                double R[9], t[3];
                kabsch3x3(&acc[7], &acc[1], &acc[4], R, t);
                double To[12];
#pragma unroll
                for (int k = 0; k < 12; ++k) To[k] = TcA[k];
#pragma unroll
                for (int i = 0; i < 3; ++i) {
#pragma unroll
                    for (int j = 0; j < 3; ++j)
                        TcA[i * 3 + j] = R[i * 3 + 0] * To[0 + j]
                                       + R[i * 3 + 1] * To[3 + j]
                                       + R[i * 3 + 2] * To[6 + j];
                    TcA[9 + i] = R[i * 3 + 0] * To[9] + R[i * 3 + 1] * To[10]
                               + R[i * 3 + 2] * To[11] + t[i];
                }
                if (sc == 0) {
#pragma unroll
                    for (int k = 0; k < 12; ++k)
                        AS(&Tcs[(b * 11 + it) * 12 + k], TcA[k]);
                    AS(&cbits[b * 16 + it], cb);
                }
            }
        }
        __syncthreads();
        if (tid < 12) TcL[tid] = (float)TcA[tid];
        __syncthreads();
    }
}

// ---------------- resolver: find freeze step k*, emit Tc(k*-1) ----------------
__global__ __launch_bounds__(64) void icp_resolve(const double* __restrict__ Tcs,
                                                  const unsigned* __restrict__ cbits,
                                                  float* __restrict__ out) {
    __shared__ int ksel;
    int tid = threadIdx.x;
    if (tid == 0) {
        int sel = 10;
        for (int t = 1; t <= 10; ++t) {
            bool all = true;
            for (int b2 = 0; b2 < NB; ++b2) all = all && (cbits[b2 * 16 + t] != 0u);
            if (all) { sel = t - 1; break; }
        }
        ksel = sel;
    }
    __syncthreads();
    if (tid < NB) {
        const double* T = Tcs + ((size_t)tid * 11 + ksel) * 12;
        float* o = out + tid * 12;
#pragma unroll
        for (int i = 0; i < 3; ++i) {
#pragma unroll
            for (int j = 0; j < 3; ++j) o[i * 4 + j] = (float)T[i * 3 + j];
            o[i * 4 + 3] = (float)T[9 + i];
        }
    }
}

extern "C" void kernel_launch(void* const* d_in, const int* in_sizes, int n_in,
                              void* d_out, int out_size, void* d_ws, size_t ws_size,
                              hipStream_t stream) {
    const float* psrc = (const float*)d_in[0];
    const float* ptgt = (const float*)d_in[1];
    float* out = (float*)d_out;

    char* ws = (char*)d_ws;
    size_t off = 0;
    double* partial = (double*)(ws + off); off += 2ull * GRID * 16 * sizeof(double);
    unsigned* flags = (unsigned*)(ws + off); off += GRID * sizeof(unsigned);
    double* Tcs   = (double*)(ws + off);   off += (size_t)NB * 11 * 12 * sizeof(double);
    unsigned* cbits = (unsigned*)(ws + off); off += NB * 16 * sizeof(unsigned);

    icp_init<<<1, 256, 0, stream>>>(flags);
    icp_main<<<GRID, THREADS, 0, stream>>>(psrc, ptgt, partial, flags, Tcs, cbits);
    icp_resolve<<<1, 64, 0, stream>>>(Tcs, cbits, out);
}

// Round 16
// 179.880 us; speedup vs baseline: 1.4792x; 1.0024x over previous
//
#include <hip/hip_runtime.h>
#include <math.h>

#define NB 8
#define NP 2048
#define GRID 256        // 256 blocks, 1/CU; batch = blk & 7 (XCD co-location)
#define THREADS 512     // 8 waves/CU
#define TOLF 1e-4f
#define EPSF 1e-12f

#define AL(p)   __hip_atomic_load((p), __ATOMIC_RELAXED, __HIP_MEMORY_SCOPE_AGENT)
#define AS(p,v) __hip_atomic_store((p), (v), __ATOMIC_RELAXED, __HIP_MEMORY_SCOPE_AGENT)

// identical fmaf structure everywhere => bit-identical transformed points
__device__ inline float3 xform_pt(const float* __restrict__ T,
                                  float x, float y, float z) {
    float3 r;
    r.x = fmaf(T[0], x, fmaf(T[1], y, fmaf(T[2], z, T[9])));
    r.y = fmaf(T[3], x, fmaf(T[4], y, fmaf(T[5], z, T[10])));
    r.z = fmaf(T[6], x, fmaf(T[7], y, fmaf(T[8], z, T[11])));
    return r;
}

// ---- 3x3 Kabsch: fp64 sums/H/det/compose, fp32 Jacobi SVD ----
__device__ void kabsch3x3(const double Spq[9], const double Sp[3], const double Sq[3],
                          double R[9], double t[3]) {
    const double invN = 1.0 / (double)NP;
    double cs[3], ct[3];
#pragma unroll
    for (int i = 0; i < 3; ++i) { cs[i] = Sp[i] * invN; ct[i] = Sq[i] * invN; }
    double Hd[9];
#pragma unroll
    for (int i = 0; i < 3; ++i)
#pragma unroll
        for (int j = 0; j < 3; ++j)
            Hd[i * 3 + j] = Spq[i * 3 + j] - (double)NP * cs[i] * ct[j];

    float Bc[3][3], V[3][3];
#pragma unroll
    for (int j = 0; j < 3; ++j)
#pragma unroll
        for (int i = 0; i < 3; ++i) {
            Bc[j][i] = (float)Hd[i * 3 + j];
            V[j][i]  = (i == j) ? 1.0f : 0.0f;
        }
    for (int sweep = 0; sweep < 12; ++sweep) {
        bool rotated = false;
        for (int p = 0; p < 2; ++p)
            for (int q = p + 1; q < 3; ++q) {
                float app = 0.f, aqq = 0.f, apq = 0.f;
#pragma unroll
                for (int i = 0; i < 3; ++i) {
                    app = fmaf(Bc[p][i], Bc[p][i], app);
                    aqq = fmaf(Bc[q][i], Bc[q][i], aqq);
                    apq = fmaf(Bc[p][i], Bc[q][i], apq);
                }
                if (apq * apq > 1e-24f + 1e-12f * app * aqq) {
                    rotated = true;
                    float tau = (aqq - app) / (2.0f * apq);
                    float tt  = (tau >= 0.f ? 1.0f : -1.0f) /
                                (fabsf(tau) + sqrtf(fmaf(tau, tau, 1.0f)));
                    float c   = 1.0f / sqrtf(fmaf(tt, tt, 1.0f));
                    float sn  = c * tt;
#pragma unroll
                    for (int i = 0; i < 3; ++i) {
                        float bp = Bc[p][i], bq = Bc[q][i];
                        Bc[p][i] = c * bp - sn * bq;
                        Bc[q][i] = sn * bp + c * bq;
                        float vp = V[p][i], vq = V[q][i];
                        V[p][i] = c * vp - sn * vq;
                        V[q][i] = sn * vp + c * vq;
                    }
                }
            }
        if (!rotated) break;
    }
    float sv[3], U[3][3];
#pragma unroll
    for (int j = 0; j < 3; ++j) {
        sv[j] = sqrtf(Bc[j][0] * Bc[j][0] + Bc[j][1] * Bc[j][1] + Bc[j][2] * Bc[j][2]);
        float inv = sv[j] > 0.f ? 1.0f / sv[j] : 0.f;
#pragma unroll
        for (int i = 0; i < 3; ++i) U[j][i] = Bc[j][i] * inv;
    }
    double detH = Hd[0] * (Hd[4] * Hd[8] - Hd[5] * Hd[7])
                - Hd[1] * (Hd[3] * Hd[8] - Hd[5] * Hd[6])
                + Hd[2] * (Hd[3] * Hd[7] - Hd[4] * Hd[6]);
    float d = (detH >= 0.0) ? 1.0f : -1.0f;
    int o[3] = {0, 1, 2};
    if (sv[o[0]] < sv[o[1]]) { int tmp = o[0]; o[0] = o[1]; o[1] = tmp; }
    if (sv[o[0]] < sv[o[2]]) { int tmp = o[0]; o[0] = o[2]; o[2] = tmp; }
    if (sv[o[1]] < sv[o[2]]) { int tmp = o[1]; o[1] = o[2]; o[2] = tmp; }
    float sg[3] = {1.0f, 1.0f, d};
#pragma unroll
    for (int i = 0; i < 3; ++i)
#pragma unroll
        for (int j = 0; j < 3; ++j) {
            float acc = 0.0f;
#pragma unroll
            for (int k = 0; k < 3; ++k) acc += sg[k] * V[o[k]][i] * U[o[k]][j];
            R[i * 3 + j] = (double)acc;
        }
#pragma unroll
    for (int i = 0; i < 3; ++i)
        t[i] = ct[i] - (R[i * 3 + 0] * cs[0] + R[i * 3 + 1] * cs[1] + R[i * 3 + 2] * cs[2]);
}

// ---------------- init: reset barrier flags ----------------
__global__ __launch_bounds__(256) void icp_init(unsigned* __restrict__ flags) {
    flags[threadIdx.x] = 0u;
}

// ---------------- main: 8 independent batches, per-batch 32-block barrier ----
// batch = blk & 7 (XCD co-location heuristic). Logical block id = b*32+sc.
// thread = (g = tid>>7: 16 srcs, slice = tid&127: 16 targets) — each
// ds_read_b128 feeds 16 srcs (~192 issue-cycles, covers LDS latency).
__global__ __launch_bounds__(THREADS, 1) void icp_main(
        const float* __restrict__ psrc, const float* __restrict__ ptgt,
        double* __restrict__ partial,    // [2][256][16] parity double-buffered
        unsigned* __restrict__ flags,    // [256] logical-id arrival (monotone it)
        double* __restrict__ Tcs,        // [8][11][12] trajectories (t=0..10)
        unsigned* __restrict__ cbits) {  // [8][16] convergence bit per iter
    __shared__ float4 tg[2112];          // targets, padded: idx = j + (j>>5)
    __shared__ float4 ps[64];            // transformed src pts (x,y,z,|P|^2)
    __shared__ float2 comb[128][66];     // [slice][src] winners
    __shared__ float2 comb2[8][66];      // stage-A merged winners
    __shared__ float  TcL[12];
    __shared__ double TcA[12];

    const int tid   = threadIdx.x;
    const int blk   = blockIdx.x;
    const int b     = blk & 7;           // batch == XCD (if round-robin dispatch)
    const int sc    = blk >> 3;          // src chunk
    const int lid   = b * 32 + sc;       // logical block id (flags/partials)
    const int slice = tid & 127;         // target slice (16 targets)
    const int g     = tid >> 7;          // src group (16 pts)
    const int w     = tid >> 6;          // wave id (stage-A merge)

    float errL = 0.0f;

    // stage all 2048 targets once (float4, padded)
    const float* tb = ptgt + b * NP * 3;
    for (int j = tid; j < NP; j += THREADS) {
        float tx = tb[3 * j + 0], ty = tb[3 * j + 1], tz = tb[3 * j + 2];
        tg[j + (j >> 5)] = make_float4(tx, ty, tz,
                                       0.5f * (tx * tx + ty * ty + tz * tz));
    }
    if (tid < 12) {
        float idv = (tid == 0 || tid == 4 || tid == 8) ? 1.0f : 0.0f;
        TcL[tid] = idv;
        TcA[tid] = (double)idv;
        if (sc == 0) AS(&Tcs[(b * 11 + 0) * 12 + tid], (double)idv);
    }
    __syncthreads();

    for (int it = 1; it <= 10; ++it) {
        // ---- transform this chunk's 64 src points with current TcL ----
        if (tid < 64) {
            const float* pp = psrc + (b * NP + sc * 64 + tid) * 3;
            float3 P = xform_pt(TcL, pp[0], pp[1], pp[2]);
            ps[tid] = make_float4(P.x, P.y, P.z,
                                  P.x * P.x + P.y * P.y + P.z * P.z);
        }
        __syncthreads();

        // ---- NN: 16 src pts/thread x 16 targets of this slice ----
        float sx[16], sy[16], sz[16], sm[16];
        int jm[16];
#pragma unroll
        for (int k = 0; k < 16; ++k) {
            float4 P = ps[g * 16 + k];
            sx[k] = P.x; sy[k] = P.y; sz[k] = P.z;
            sm[k] = INFINITY; jm[k] = 0;
        }
        const int jbase = slice * 16;
        const int base  = jbase + (slice >> 1);   // tg idx of target jbase
#pragma unroll 2
        for (int i = 0; i < 16; ++i) {
            float4 t = tg[base + i];
            int j = jbase + i;
#pragma unroll
            for (int k = 0; k < 16; ++k) {
                float s = fmaf(-sx[k], t.x, fmaf(-sy[k], t.y, fmaf(-sz[k], t.z, t.w)));
                if (s < sm[k]) { sm[k] = s; jm[k] = j; }   // ascending j: first-min
            }
        }
#pragma unroll
        for (int k = 0; k < 16; ++k)
            comb[slice][g * 16 + k] = make_float2(sm[k], __int_as_float(jm[k]));
        __syncthreads();

        // ---- stage A: each wave merges its 16 slices (ascending order) ----
        {
            int l = tid & 63;
            float fb = INFINITY; int fj = 0;
#pragma unroll
            for (int q = 0; q < 16; ++q) {
                float2 e = comb[w * 16 + q][l];
                if (e.x < fb) { fb = e.x; fj = __float_as_int(e.y); }
            }
            comb2[w][l] = make_float2(fb, __int_as_float(fj));
        }
        __syncthreads();

        double* pbase = partial + (size_t)(it & 1) * GRID * 16;

        // ---- wave 0: final merge + fp64 sums + publish; wave 1: poll ----
        if (tid < 64) {
            float fb = INFINITY; int fj = 0;
#pragma unroll
            for (int q = 0; q < 8; ++q) {            // ascending: first-min
                float2 e = comb2[q][tid];
                if (e.x < fb) { fb = e.x; fj = __float_as_int(e.y); }
            }
            float4 P = ps[tid];
            float d2 = fmaf(2.0f, fb, P.w);
            float dist = sqrtf(fmaxf(d2, EPSF));
            float4 Q = tg[fj + (fj >> 5)];

            double v[16];
            v[0] = dist;
            v[1] = P.x; v[2] = P.y; v[3] = P.z;
            v[4] = Q.x; v[5] = Q.y; v[6] = Q.z;
            v[7]  = (double)P.x * Q.x; v[8]  = (double)P.x * Q.y; v[9]  = (double)P.x * Q.z;
            v[10] = (double)P.y * Q.x; v[11] = (double)P.y * Q.y; v[12] = (double)P.y * Q.z;
            v[13] = (double)P.z * Q.x; v[14] = (double)P.z * Q.y; v[15] = (double)P.z * Q.z;
#pragma unroll
            for (int k = 0; k < 16; ++k) {
                double x = v[k];
#pragma unroll
                for (int off = 32; off > 0; off >>= 1) x += __shfl_down(x, off);
                v[k] = x;
            }
            if (tid == 0) {
                double* dst = pbase + lid * 16;
#pragma unroll
                for (int k = 0; k < 16; ++k) AS(dst + k, v[k]);
                asm volatile("s_waitcnt vmcnt(0)" ::: "memory");
                AS(&flags[lid], (unsigned)it);
            }
        } else if (tid < 128) {
            int l = tid - 64;
            bool ok;
            do {
                ok = (l < 32) ? (AL(&flags[b * 32 + l]) >= (unsigned)it) : true;
                if (!__all(ok)) __builtin_amdgcn_s_sleep(1); else break;
            } while (true);
        }
        __syncthreads();

        // ---- lanes 0-31: read batch partials + fixed-order reduce + Kabsch ----
        if (tid < 32) {
            double acc[16];
            const double* pp2 = pbase + (b * 32 + tid) * 16;
#pragma unroll
            for (int k = 0; k < 16; ++k) acc[k] = AL(pp2 + k);
#pragma unroll
            for (int k = 0; k < 16; ++k) {
                double x = acc[k];
                x += __shfl_down(x, 16);
                x += __shfl_down(x, 8);
                x += __shfl_down(x, 4);
                x += __shfl_down(x, 2);
                x += __shfl_down(x, 1);
                acc[k] = x;
            }
            if (tid == 0) {
                float errnew = (float)(acc[0] * (1.0 / (double)NP));
                unsigned cb = (fabsf(errnew - errL) < TOLF) ? 1u : 0u;
                errL = errnew;
                double R[9], t[3];
                kabsch3x3(&acc[7], &acc[1], &acc[4], R, t);
                double To[12];
#pragma unroll
                for (int k = 0; k < 12; ++k) To[k] = TcA[k];
#pragma unroll
                for (int i = 0; i < 3; ++i) {
#pragma unroll
                    for (int j = 0; j < 3; ++j)
                        TcA[i * 3 + j] = R[i * 3 + 0] * To[0 + j]
                                       + R[i * 3 + 1] * To[3 + j]
                                       + R[i * 3 + 2] * To[6 + j];
                    TcA[9 + i] = R[i * 3 + 0] * To[9] + R[i * 3 + 1] * To[10]
                               + R[i * 3 + 2] * To[11] + t[i];
                }
                if (sc == 0) {
#pragma unroll
                    for (int k = 0; k < 12; ++k)
                        AS(&Tcs[(b * 11 + it) * 12 + k], TcA[k]);
                    AS(&cbits[b * 16 + it], cb);
                }
            }
        }
        __syncthreads();
        if (tid < 12) TcL[tid] = (float)TcA[tid];
        __syncthreads();
    }
}

// ---------------- resolver: find freeze step k*, emit Tc(k*-1) ----------------
__global__ __launch_bounds__(64) void icp_resolve(const double* __restrict__ Tcs,
                                                  const unsigned* __restrict__ cbits,
                                                  float* __restrict__ out) {
    __shared__ int ksel;
    int tid = threadIdx.x;
    if (tid == 0) {
        int sel = 10;
        for (int t = 1; t <= 10; ++t) {
            bool all = true;
            for (int b2 = 0; b2 < NB; ++b2) all = all && (cbits[b2 * 16 + t] != 0u);
            if (all) { sel = t - 1; break; }
        }
        ksel = sel;
    }
    __syncthreads();
    if (tid < NB) {
        const double* T = Tcs + ((size_t)tid * 11 + ksel) * 12;
        float* o = out + tid * 12;
#pragma unroll
        for (int i = 0; i < 3; ++i) {
#pragma unroll
            for (int j = 0; j < 3; ++j) o[i * 4 + j] = (float)T[i * 3 + j];
            o[i * 4 + 3] = (float)T[9 + i];
        }
    }
}

extern "C" void kernel_launch(void* const* d_in, const int* in_sizes, int n_in,
                              void* d_out, int out_size, void* d_ws, size_t ws_size,
                              hipStream_t stream) {
    const float* psrc = (const float*)d_in[0];
    const float* ptgt = (const float*)d_in[1];
    float* out = (float*)d_out;

    char* ws = (char*)d_ws;
    size_t off = 0;
    double* partial = (double*)(ws + off); off += 2ull * GRID * 16 * sizeof(double);
    unsigned* flags = (unsigned*)(ws + off); off += GRID * sizeof(unsigned);
    double* Tcs   = (double*)(ws + off);   off += (size_t)NB * 11 * 12 * sizeof(double);
    unsigned* cbits = (unsigned*)(ws + off); off += NB * 16 * sizeof(unsigned);

    icp_init<<<1, 256, 0, stream>>>(flags);
    icp_main<<<GRID, THREADS, 0, stream>>>(psrc, ptgt, partial, flags, Tcs, cbits);
    icp_resolve<<<1, 64, 0, stream>>>(Tcs, cbits, out);
}